// Round 3
// baseline (719.638 us; speedup 1.0000x reference)
//
#include <hip/hip_runtime.h>
#include <hip/hip_bf16.h>
#include <math.h>

// Problem constants: B=4, H=16, L=4096, D=64, S=128
constexpr int BB = 4;
constexpr int HH = 16;
constexpr int LL = 4096;
constexpr int DD = 64;
constexpr int SS = 128;

// R2 post-mortem: LDS-instruction-rate bound (9.9 cyc/ds_read_b128, 93% of
// LDS ceiling). Fix: (a) 2 rows/thread -> 8 FMAs per codebook read,
// (b) split codebook stream across LDS pipe (s<S_LDS) and VMEM pipe
// (s>=S_LDS, wave-uniform global_load_dwordx4 hitting L1/L2), interleaved
// so lgkmcnt and vmcnt streams overlap. SMEM is NOT used: s_load shares
// lgkmcnt with ds_read and is out-of-order -> forces lgkmcnt(0) serialization.
constexpr int S_LDS = 56;                // codebook rows staged in LDS (14 KB)
constexpr int S_VMEM = SS - S_LDS;       // 72 rows streamed via VMEM
constexpr int ROWS_PER_BLOCK = 512;      // 256 threads x 2 rows

__global__ __launch_bounds__(256, 2) void quantizer_kernel(
    const float* __restrict__ x,   // [B,H,L,D]
    const float* __restrict__ c,   // [H,S,D]
    float* __restrict__ out,       // [B,H,L,S] one-hot
    float* __restrict__ out_c)     // [H,S,D] copy of c
{
    const int tid = threadIdx.x;
    const int blk = blockIdx.x;
    const long long row0 = (long long)blk * ROWS_PER_BLOCK;
    // h uniform per block: 512 | 4096
    const int h = (int)((row0 >> 12) & (HH - 1));
    const float* __restrict__ chead = c + (size_t)h * SS * DD;

    __shared__ float4 cb[S_LDS * DD / 4];   // 896 float4 = 14 KB
    __shared__ int amax[ROWS_PER_BLOCK];    // 2 KB

    // ---- stage LDS portion of codebook (coalesced float4) ----
    {
        const float4* __restrict__ csrc = (const float4*)chead;
        for (int i = tid; i < S_LDS * DD / 4; i += 256)
            cb[i] = csrc[i];
    }

    // ---- load both x rows into registers (coalesced across threads) ----
    float xa[DD], xb[DD];
    {
        const float4* __restrict__ xpA = (const float4*)(x + (size_t)(row0 + tid) * DD);
        const float4* __restrict__ xpB = (const float4*)(x + (size_t)(row0 + 256 + tid) * DD);
        #pragma unroll
        for (int i = 0; i < DD / 4; ++i) {
            float4 v = xpA[i];
            xa[4*i+0] = v.x; xa[4*i+1] = v.y; xa[4*i+2] = v.z; xa[4*i+3] = v.w;
            float4 w = xpB[i];
            xb[4*i+0] = w.x; xb[4*i+1] = w.y; xb[4*i+2] = w.z; xb[4*i+3] = w.w;
        }
    }

    __syncthreads();

    // Opaque zero in a VGPR: makes the codebook address formally lane-varying
    // so the compiler emits global_load_dwordx4 (VMEM pipe), never s_load.
    int vzero;
    asm volatile("v_mov_b32 %0, 0" : "=v"(vzero));
    const float4* __restrict__ cvm = (const float4*)chead + vzero;

    float bestA = -INFINITY, bestB = -INFINITY;
    int idxA = 0, idxB = 0;

    // branchless argmax update with first-index tie-break (np.argmax semantics;
    // needed because the scan order below is not ascending in s)
    auto upd = [](float& best, int& bidx, float d, int s) {
        bool better = (d > best) || (d == best && s < bidx);
        best = better ? d : best;
        bidx = better ? s : bidx;
    };

    // ---- interleaved dual-pipe scan: each iteration does one VMEM row,
    //      and (for i < S_LDS) one LDS row ----
    for (int i = 0; i < S_VMEM; ++i) {
        {   // VMEM row s = S_LDS + i  (wave-uniform global_load_dwordx4)
            const int s = S_LDS + i;
            const float4* __restrict__ cr = cvm + s * (DD / 4);
            float a0 = 0.f, a1 = 0.f, a2 = 0.f, a3 = 0.f;
            float b0 = 0.f, b1 = 0.f, b2 = 0.f, b3 = 0.f;
            #pragma unroll
            for (int d4 = 0; d4 < DD / 4; ++d4) {
                float4 cv = cr[d4];
                a0 = fmaf(xa[4*d4+0], cv.x, a0);
                a1 = fmaf(xa[4*d4+1], cv.y, a1);
                a2 = fmaf(xa[4*d4+2], cv.z, a2);
                a3 = fmaf(xa[4*d4+3], cv.w, a3);
                b0 = fmaf(xb[4*d4+0], cv.x, b0);
                b1 = fmaf(xb[4*d4+1], cv.y, b1);
                b2 = fmaf(xb[4*d4+2], cv.z, b2);
                b3 = fmaf(xb[4*d4+3], cv.w, b3);
            }
            upd(bestA, idxA, (a0 + a1) + (a2 + a3), s);
            upd(bestB, idxB, (b0 + b1) + (b2 + b3), s);
        }
        if (i < S_LDS) {   // LDS row s = i (broadcast ds_read_b128)
            const float4* __restrict__ cr = &cb[i * (DD / 4)];
            float a0 = 0.f, a1 = 0.f, a2 = 0.f, a3 = 0.f;
            float b0 = 0.f, b1 = 0.f, b2 = 0.f, b3 = 0.f;
            #pragma unroll
            for (int d4 = 0; d4 < DD / 4; ++d4) {
                float4 cv = cr[d4];
                a0 = fmaf(xa[4*d4+0], cv.x, a0);
                a1 = fmaf(xa[4*d4+1], cv.y, a1);
                a2 = fmaf(xa[4*d4+2], cv.z, a2);
                a3 = fmaf(xa[4*d4+3], cv.w, a3);
                b0 = fmaf(xb[4*d4+0], cv.x, b0);
                b1 = fmaf(xb[4*d4+1], cv.y, b1);
                b2 = fmaf(xb[4*d4+2], cv.z, b2);
                b3 = fmaf(xb[4*d4+3], cv.w, b3);
            }
            upd(bestA, idxA, (a0 + a1) + (a2 + a3), i);
            upd(bestB, idxB, (b0 + b1) + (b2 + b3), i);
        }
    }

    // ---- share argmaxes, then cooperatively write one-hot (coalesced) ----
    amax[tid] = idxA;
    amax[tid + 256] = idxB;
    __syncthreads();

    // Block owns rows [row0, row0+512): 512*32 = 16384 float4s.
    float4* __restrict__ op = (float4*)(out + (size_t)row0 * SS);
    #pragma unroll 4
    for (int i = tid; i < ROWS_PER_BLOCK * (SS / 4); i += 256) {
        const int rr = i >> 5;          // row within block (32 float4 per row)
        const int s0 = (i & 31) * 4;    // first s covered by this float4
        const int am = amax[rr];
        float4 v;
        v.x = (s0 + 0 == am) ? 1.f : 0.f;
        v.y = (s0 + 1 == am) ? 1.f : 0.f;
        v.z = (s0 + 2 == am) ? 1.f : 0.f;
        v.w = (s0 + 3 == am) ? 1.f : 0.f;
        op[i] = v;
    }

    // ---- copy c to second output region (first 128 blocks) ----
    if (blk < 128) {
        const float4* __restrict__ src = (const float4*)c;
        float4* __restrict__ dst = (float4*)out_c;
        const int idx = blk * 256 + tid;
        dst[idx] = src[idx];
    }
}

extern "C" void kernel_launch(void* const* d_in, const int* in_sizes, int n_in,
                              void* d_out, int out_size, void* d_ws, size_t ws_size,
                              hipStream_t stream) {
    const float* x = (const float*)d_in[0];   // [B,H,L,D] fp32
    const float* c = (const float*)d_in[1];   // [H,S,D]   fp32
    float* out = (float*)d_out;               // onehot [B,H,L,S] then c [H,S,D]
    float* out_c = out + (size_t)BB * HH * LL * SS;

    const int rows = BB * HH * LL;                 // 262144
    const int blocks = rows / ROWS_PER_BLOCK;      // 512
    quantizer_kernel<<<blocks, 256, 0, stream>>>(x, c, out, out_c);
}

// Round 4
// 310.108 us; speedup vs baseline: 2.3206x; 2.3206x over previous
//
#include <hip/hip_runtime.h>
#include <hip/hip_bf16.h>
#include <math.h>

// Problem constants: B=4, H=16, L=4096, D=64, S=128
constexpr int BB = 4;
constexpr int HH = 16;
constexpr int LL = 4096;
constexpr int DD = 64;
constexpr int SS = 128;

// R3 post-mortem: 2 rows/thread spilled (xa+xb=128 VGPR vs 128 cap ->
// 1.15 GB scratch reloads). R4: back to 1 row/thread (no spill, ~95 VGPR),
// keep ONLY the dual-pipe s-split: s<64 from LDS (lgkmcnt pipe, broadcast
// ds_read_b128), s>=64 via wave-uniform global_load_dwordx4 (vmcnt pipe,
// L1/L2-resident codebook). Interleaved per-iteration so both pipes run
// concurrently within each wave. SMEM deliberately avoided (s_load is
// out-of-order on lgkmcnt -> serializes against ds_read).
constexpr int S_LDS = 64;                // codebook rows staged in LDS (16 KB)
constexpr int S_VMEM = SS - S_LDS;       // 64 rows streamed via VMEM

__global__ __launch_bounds__(256, 4) void quantizer_kernel(
    const float* __restrict__ x,   // [B,H,L,D]
    const float* __restrict__ c,   // [H,S,D]
    float* __restrict__ out,       // [B,H,L,S] one-hot
    float* __restrict__ out_c)     // [H,S,D] copy of c
{
    const int tid = threadIdx.x;
    const int blk = blockIdx.x;
    const long long row0 = (long long)blk * 256;
    const long long r = row0 + tid;

    // h uniform per block: 256 | 4096
    const int h = (int)((row0 >> 12) & (HH - 1));
    const float* __restrict__ chead = c + (size_t)h * SS * DD;

    __shared__ float4 cb[S_LDS * DD / 4];   // 1024 float4 = 16 KB
    __shared__ int amax[256];               // 1 KB

    // ---- stage LDS portion of codebook (coalesced float4) ----
    {
        const float4* __restrict__ csrc = (const float4*)chead;
        #pragma unroll
        for (int i = 0; i < S_LDS * DD / 4 / 256; ++i)
            cb[tid + i * 256] = csrc[tid + i * 256];
    }

    // ---- load x row into registers (16 coalesced float4 loads) ----
    float xr[DD];
    {
        const float4* __restrict__ xp = (const float4*)(x + (size_t)r * DD);
        #pragma unroll
        for (int i = 0; i < DD / 4; ++i) {
            float4 v = xp[i];
            xr[4*i+0] = v.x; xr[4*i+1] = v.y; xr[4*i+2] = v.z; xr[4*i+3] = v.w;
        }
    }

    __syncthreads();

    // Opaque zero in a VGPR: makes the codebook address formally lane-varying
    // so the compiler emits global_load_dwordx4 (vmcnt pipe), never s_load.
    int vzero;
    asm volatile("v_mov_b32 %0, 0" : "=v"(vzero));
    const float4* __restrict__ cvm = (const float4*)chead + vzero;

    float best = -INFINITY;
    int bidx = 0;

    // branchless argmax update with first-index tie-break (np.argmax
    // semantics; needed because the scan order is not ascending in s)
    auto upd = [&](float d, int s) {
        bool better = (d > best) || (d == best && s < bidx);
        best = better ? d : best;
        bidx = better ? s : bidx;
    };

    // ---- interleaved dual-pipe scan: one VMEM row + one LDS row per iter ----
    #pragma unroll 2
    for (int i = 0; i < S_LDS; ++i) {
        {   // VMEM row s = S_LDS + i (wave-uniform global_load_dwordx4)
            const int s = S_LDS + i;
            const float4* __restrict__ cr = cvm + s * (DD / 4);
            float a0 = 0.f, a1 = 0.f, a2 = 0.f, a3 = 0.f;
            #pragma unroll
            for (int d4 = 0; d4 < DD / 4; ++d4) {
                float4 cv = cr[d4];
                a0 = fmaf(xr[4*d4+0], cv.x, a0);
                a1 = fmaf(xr[4*d4+1], cv.y, a1);
                a2 = fmaf(xr[4*d4+2], cv.z, a2);
                a3 = fmaf(xr[4*d4+3], cv.w, a3);
            }
            upd((a0 + a1) + (a2 + a3), s);
        }
        {   // LDS row s = i (broadcast ds_read_b128, conflict-free)
            const float4* __restrict__ cr = &cb[i * (DD / 4)];
            float a0 = 0.f, a1 = 0.f, a2 = 0.f, a3 = 0.f;
            #pragma unroll
            for (int d4 = 0; d4 < DD / 4; ++d4) {
                float4 cv = cr[d4];
                a0 = fmaf(xr[4*d4+0], cv.x, a0);
                a1 = fmaf(xr[4*d4+1], cv.y, a1);
                a2 = fmaf(xr[4*d4+2], cv.z, a2);
                a3 = fmaf(xr[4*d4+3], cv.w, a3);
            }
            upd((a0 + a1) + (a2 + a3), i);
        }
    }

    // ---- share argmaxes, then cooperatively write one-hot (coalesced) ----
    amax[tid] = bidx;
    __syncthreads();

    // Block owns rows [row0, row0+256): 256*32 = 8192 float4s.
    float4* __restrict__ op = (float4*)(out + (size_t)row0 * SS);
    #pragma unroll 4
    for (int i = tid; i < 8192; i += 256) {
        const int rr = i >> 5;          // row within block (32 float4 per row)
        const int s0 = (i & 31) * 4;    // first s covered by this float4
        const int am = amax[rr];
        float4 v;
        v.x = (s0 + 0 == am) ? 1.f : 0.f;
        v.y = (s0 + 1 == am) ? 1.f : 0.f;
        v.z = (s0 + 2 == am) ? 1.f : 0.f;
        v.w = (s0 + 3 == am) ? 1.f : 0.f;
        op[i] = v;
    }

    // ---- copy c to second output region (first 128 blocks) ----
    // H*S*D = 131072 floats = 32768 float4s = 128 blocks * 256 threads
    if (blk < 128) {
        const float4* __restrict__ src = (const float4*)c;
        float4* __restrict__ dst = (float4*)out_c;
        const int idx = blk * 256 + tid;
        dst[idx] = src[idx];
    }
}

extern "C" void kernel_launch(void* const* d_in, const int* in_sizes, int n_in,
                              void* d_out, int out_size, void* d_ws, size_t ws_size,
                              hipStream_t stream) {
    const float* x = (const float*)d_in[0];   // [B,H,L,D] fp32
    const float* c = (const float*)d_in[1];   // [H,S,D]   fp32
    float* out = (float*)d_out;               // onehot [B,H,L,S] then c [H,S,D]
    float* out_c = out + (size_t)BB * HH * LL * SS;

    const int rows = BB * HH * LL;            // 262144
    const int blocks = rows / 256;            // 1024
    quantizer_kernel<<<blocks, 256, 0, stream>>>(x, c, out, out_c);
}

// Round 5
// 206.614 us; speedup vs baseline: 3.4830x; 1.5009x over previous
//
#include <hip/hip_runtime.h>
#include <hip/hip_bf16.h>
#include <math.h>

// Problem constants: B=4, H=16, L=4096, D=64, S=128
constexpr int BB = 4;
constexpr int HH = 16;
constexpr int LL = 4096;
constexpr int DD = 64;
constexpr int SS = 128;

// R4 post-mortem: wave-uniform VMEM codebook loads return at ~16 cyc/instr
// (L1 64B/cyc) -- slower than 10-cyc LDS broadcast; dual-pipe regressed.
// R2's wall: 1 row/thread means every thread streams all 32KB of codebook
// through the LDS return path (8.6 GB total = ~125us floor).
// R5: register-tiled GEMM per block: [128 rows x 64k]x[64k x 128 codes],
// 8x8 tile per thread (16x16 thread grid). Per k: 4 ds_read_b128 feed 64
// FMAs (16x reuse) -> LDS traffic 2.1 GB (~36us), VALU floor 27us underneath.
constexpr int BM = 128;          // rows per block
constexpr int PP = 17;           // padded stride for partial-argmax buffers

__global__ __launch_bounds__(256) void quantizer_kernel(
    const float* __restrict__ x,   // [B,H,L,D]
    const float* __restrict__ c,   // [H,S,D]
    float* __restrict__ out,       // [B,H,L,S] one-hot
    float* __restrict__ out_c)     // [H,S,D] copy of c
{
    __shared__ float xs[DD * BM];  // x tile, k-major [64][128] = 32 KB
    __shared__ float cs[DD * SS];  // c tile, k-major [64][128] = 32 KB
    __shared__ int amax[BM];

    const int tid = threadIdx.x;
    const int blk = blockIdx.x;
    const long long r0 = (long long)blk * BM;
    // h uniform per block (128 | 4096)
    const int h = (int)((r0 >> 12) & (HH - 1));
    const float* __restrict__ chead = c + (size_t)h * SS * DD;

    // ---- stage both tiles transposed to k-major ----
    // mapping: row in low 7 bits -> LDS write addr bank = row%32 -> 2-way
    // (free); global read is 64B-line strided but L1 absorbs (16KB working set).
    {
        const float4* __restrict__ xg = (const float4*)(x + (size_t)r0 * DD);
        const float4* __restrict__ cg = (const float4*)chead;
        #pragma unroll
        for (int it = 0; it < 8; ++it) {
            const int idx = tid + it * 256;   // 0..2047
            const int row = idx & 127;
            const int d4  = idx >> 7;         // 0..15
            float4 v = xg[row * 16 + d4];
            xs[(4 * d4 + 0) * BM + row] = v.x;
            xs[(4 * d4 + 1) * BM + row] = v.y;
            xs[(4 * d4 + 2) * BM + row] = v.z;
            xs[(4 * d4 + 3) * BM + row] = v.w;
            float4 w = cg[row * 16 + d4];     // row == code index here
            cs[(4 * d4 + 0) * SS + row] = w.x;
            cs[(4 * d4 + 1) * SS + row] = w.y;
            cs[(4 * d4 + 2) * SS + row] = w.z;
            cs[(4 * d4 + 3) * SS + row] = w.w;
        }
    }
    __syncthreads();

    const int m0 = tid >> 4;   // row group 0..15   (wave: 4 values -> x broadcast)
    const int n0 = tid & 15;   // code group 0..15  (wave: 16 values -> c 4-way)

    float acc[8][8] = {};      // 64 accumulators

    #pragma unroll 2
    for (int k = 0; k < DD; ++k) {
        const float4 xa = *(const float4*)&xs[k * BM + m0 * 8];
        const float4 xb = *(const float4*)&xs[k * BM + m0 * 8 + 4];
        const float4 ca = *(const float4*)&cs[k * SS + n0 * 8];
        const float4 cb = *(const float4*)&cs[k * SS + n0 * 8 + 4];
        const float xv[8] = {xa.x, xa.y, xa.z, xa.w, xb.x, xb.y, xb.z, xb.w};
        const float cv[8] = {ca.x, ca.y, ca.z, ca.w, cb.x, cb.y, cb.z, cb.w};
        #pragma unroll
        for (int i = 0; i < 8; ++i)
            #pragma unroll
            for (int j = 0; j < 8; ++j)
                acc[i][j] = fmaf(xv[i], cv[j], acc[i][j]);
    }

    __syncthreads();           // k-loop done; reuse xs region for partials
    float* pval = xs;                      // [BM][PP] floats
    int*   pidx = (int*)(xs + BM * PP);    // [BM][PP] ints (total 4352 < 8192)

    // per-thread partial argmax over its 8 codes for each of its 8 rows.
    // ascending j + strict > == first-index tie-break within the tile.
    #pragma unroll
    for (int i = 0; i < 8; ++i) {
        float bv = acc[i][0];
        int bj = 0;
        #pragma unroll
        for (int j = 1; j < 8; ++j)
            if (acc[i][j] > bv) { bv = acc[i][j]; bj = j; }
        const int row = m0 * 8 + i;
        pval[row * PP + n0] = bv;
        pidx[row * PP + n0] = n0 * 8 + bj;
    }
    __syncthreads();

    // cross-tile reduce: ascending n0 + strict > keeps first index on ties
    if (tid < BM) {
        float bv = pval[tid * PP];
        int bi = pidx[tid * PP];
        #pragma unroll
        for (int t = 1; t < 16; ++t) {
            const float v = pval[tid * PP + t];
            const int ix = pidx[tid * PP + t];
            if (v > bv) { bv = v; bi = ix; }
        }
        amax[tid] = bi;
    }
    __syncthreads();

    // ---- cooperative coalesced one-hot write: 128 rows * 32 float4 ----
    float4* __restrict__ op = (float4*)(out + (size_t)r0 * SS);
    #pragma unroll 4
    for (int i = tid; i < BM * (SS / 4); i += 256) {
        const int rr = i >> 5;          // row within block
        const int s0 = (i & 31) * 4;    // first s of this float4
        const int am = amax[rr];
        float4 v;
        v.x = (s0 + 0 == am) ? 1.f : 0.f;
        v.y = (s0 + 1 == am) ? 1.f : 0.f;
        v.z = (s0 + 2 == am) ? 1.f : 0.f;
        v.w = (s0 + 3 == am) ? 1.f : 0.f;
        op[i] = v;
    }

    // ---- copy c to second output region (first 128 blocks) ----
    // H*S*D = 131072 floats = 32768 float4s = 128 blocks * 256 threads
    if (blk < 128) {
        const float4* __restrict__ src = (const float4*)c;
        float4* __restrict__ dst = (float4*)out_c;
        const int idx = blk * 256 + tid;
        dst[idx] = src[idx];
    }
}

extern "C" void kernel_launch(void* const* d_in, const int* in_sizes, int n_in,
                              void* d_out, int out_size, void* d_ws, size_t ws_size,
                              hipStream_t stream) {
    const float* x = (const float*)d_in[0];   // [B,H,L,D] fp32
    const float* c = (const float*)d_in[1];   // [H,S,D]   fp32
    float* out = (float*)d_out;               // onehot [B,H,L,S] then c [H,S,D]
    float* out_c = out + (size_t)BB * HH * LL * SS;

    const int rows = BB * HH * LL;            // 262144
    const int blocks = rows / BM;             // 2048
    quantizer_kernel<<<blocks, 256, 0, stream>>>(x, c, out, out_c);
}